// Round 1
// baseline (1543.871 us; speedup 1.0000x reference)
//
#include <hip/hip_runtime.h>
#include <hip/hip_bf16.h>

#define N_IN   200000
#define N_OUT  600000
#define KOFF   27
#define PPAIR  150000
#define NPAIR  (KOFF * PPAIR)       // 4,050,000
#define C      96
#define BN_EPS 1e-5f

using bf16x8 = __attribute__((ext_vector_type(8))) __bf16;
using f32x4  = __attribute__((ext_vector_type(4))) float;

static __device__ __forceinline__ unsigned short f2b(float x) {
    __hip_bfloat16 h = __float2bfloat16(x);
    return *reinterpret_cast<unsigned short*>(&h);
}
static __device__ __forceinline__ float b_lo(unsigned int u) { return __uint_as_float(u << 16); }
static __device__ __forceinline__ float b_hi(unsigned int u) { return __uint_as_float(u & 0xffff0000u); }

// ---- feats fp32 -> bf16, 8 elems/thread. 19,200,000 = 9375*256*8 exactly.
__global__ void cvt_feats(const float* __restrict__ src, unsigned short* __restrict__ dst) {
    int t = blockIdx.x * 256 + threadIdx.x;
    const float4* s4 = (const float4*)src;
    float4 a = s4[2 * t], b = s4[2 * t + 1];
    union { unsigned short u[8]; uint4 v; } r;
    r.u[0] = f2b(a.x); r.u[1] = f2b(a.y); r.u[2] = f2b(a.z); r.u[3] = f2b(a.w);
    r.u[4] = f2b(b.x); r.u[5] = f2b(b.y); r.u[6] = f2b(b.z); r.u[7] = f2b(b.w);
    ((uint4*)dst)[t] = r.v;
}

// ---- weight [k][c_in][c_out] fp32 -> wt [k][c_out][c_in] bf16
__global__ void cvt_w(const float* __restrict__ w, unsigned short* __restrict__ wt) {
    int t = blockIdx.x * 256 + threadIdx.x;   // 972*256 = 248832 exactly
    int k = t / 9216;
    int rem = t - k * 9216;
    int o = rem / 96;
    int i = rem - o * 96;
    wt[t] = f2b(w[k * 9216 + i * 96 + o]);
}

// ---- counting sort of out_idx --------------------------------------------
// hist + local rank in ONE pass: the atomicAdd return value IS the local rank.
__global__ void k_hist(const int* __restrict__ out_idx, int* __restrict__ counts,
                       int* __restrict__ lrank) {
    int t = blockIdx.x * 256 + threadIdx.x;
    if (t < NPAIR) lrank[t] = atomicAdd(&counts[out_idx[t]], 1);
}

__global__ void k_bsum(const int* __restrict__ counts, int* __restrict__ bsum) {
    __shared__ int ls[256];
    int b = blockIdx.x, t = threadIdx.x;
    int base = b * 1024 + t * 4;
    int s = 0;
#pragma unroll
    for (int j = 0; j < 4; j++) { int i = base + j; if (i < N_OUT) s += counts[i]; }
    ls[t] = s;
    __syncthreads();
    for (int off = 128; off > 0; off >>= 1) {
        if (t < off) ls[t] += ls[t + off];
        __syncthreads();
    }
    if (t == 0) bsum[b] = ls[0];
}

__global__ void k_scan_bsum(const int* __restrict__ bsum, int* __restrict__ bsum_ex) {
    __shared__ int sc[1024];
    int t = threadIdx.x;
    int v = (t < 586) ? bsum[t] : 0;
    sc[t] = v;
    __syncthreads();
    for (int off = 1; off < 1024; off <<= 1) {
        int add = (t >= off) ? sc[t - off] : 0;
        __syncthreads();
        sc[t] += add;
        __syncthreads();
    }
    bsum_ex[t] = sc[t] - v;   // exclusive
}

__global__ void k_scan_local(const int* __restrict__ counts, const int* __restrict__ bsum_ex,
                             int* __restrict__ csr) {
    __shared__ int sc[256];
    int b = blockIdx.x, t = threadIdx.x;
    int base = b * 1024 + t * 4;
    int c[4];
    int s = 0;
#pragma unroll
    for (int j = 0; j < 4; j++) {
        int i = base + j;
        c[j] = (i < N_OUT) ? counts[i] : 0;
        s += c[j];
    }
    sc[t] = s;
    __syncthreads();
    for (int off = 1; off < 256; off <<= 1) {
        int add = (t >= off) ? sc[t - off] : 0;
        __syncthreads();
        sc[t] += add;
        __syncthreads();
    }
    int run = bsum_ex[b] + sc[t] - s;
#pragma unroll
    for (int j = 0; j < 4; j++) {
        int i = base + j;
        if (i < N_OUT) {
            csr[i] = run;
            run += c[j];
            if (i == N_OUT - 1) csr[N_OUT] = run;
        }
    }
}

// ---- Phase A: gather -> transposed MFMA -> direct per-lane scatter --------
// mfma(b, a, acc) computes D^T = W^T . feats^T, so each lane holds
// col = pair = lane&15 (constant across n) and rows = channels
// n*16 + quad*4 + {0..3}. Each lane packs 4 floats -> 4 bf16 and stores 8B
// straight into its pair's contrib row: NO LDS repack, no extra barrier.
__global__ __launch_bounds__(256, 6) void contrib_k(
    const unsigned short* __restrict__ fb,   // feats bf16 [N_IN][96]
    const unsigned short* __restrict__ wt,   // weight bf16 [27][96(out)][96(in)]
    const int* __restrict__ in_idx,
    const int* __restrict__ out_idx,
    const int* __restrict__ csr,
    const int* __restrict__ lrank,
    unsigned short* __restrict__ contrib)    // [NPAIR][96] bf16, sorted by out_idx
{
    __shared__ int s_g[64];
    __shared__ int s_rank[64];

    const int t    = threadIdx.x;
    const int k    = blockIdx.y;
    const int row0 = blockIdx.x * 64;
    const long kp  = (long)k * PPAIR;

    if (t < 64) {
        int p  = row0 + t;
        int pc = (p < PPAIR) ? p : (PPAIR - 1);
        s_g[t]    = in_idx[kp + pc];
        s_rank[t] = (p < PPAIR) ? (csr[out_idx[kp + p]] + lrank[kp + p]) : -1;
    }
    __syncthreads();

    const int wave = t >> 6, lane = t & 63;
    const int quad = lane >> 4, l16 = lane & 15;

    const unsigned short* arow  = fb + (size_t)s_g[wave * 16 + l16] * 96 + quad * 8;
    const unsigned short* bbase = wt + (size_t)k * 9216 + l16 * 96 + quad * 8;

    f32x4 acc[6];
#pragma unroll
    for (int n = 0; n < 6; n++) acc[n] = (f32x4){0.f, 0.f, 0.f, 0.f};

#pragma unroll
    for (int kk = 0; kk < 3; kk++) {
        bf16x8 a = *(const bf16x8*)(arow + kk * 32);
#pragma unroll
        for (int n = 0; n < 6; n++) {
            bf16x8 b = *(const bf16x8*)(bbase + n * 16 * 96 + kk * 32);
            // swapped operands: acc[n] = (W^T)(feats^T) block -> D^T
            acc[n] = __builtin_amdgcn_mfma_f32_16x16x32_bf16(b, a, acc[n], 0, 0, 0);
        }
    }

    const int rk = s_rank[wave * 16 + l16];
    if (rk >= 0) {
        unsigned short* crow = contrib + (size_t)rk * 96 + quad * 4;
#pragma unroll
        for (int n = 0; n < 6; n++) {
            uint2 v;
            v.x = (unsigned)f2b(acc[n][0]) | ((unsigned)f2b(acc[n][1]) << 16);
            v.y = (unsigned)f2b(acc[n][2]) | ((unsigned)f2b(acc[n][3]) << 16);
            *(uint2*)(crow + n * 16) = v;   // channels n*16 + quad*4 .. +3
        }
    }
}

// ---- Phase B: sequential-slab reduction + fused BN stats ------------------
// block 384: rl = t/24 in [0,16) rows in flight, c4 = t%24 -> 4 channels/lane.
__global__ __launch_bounds__(384) void reduce_bn(
    const unsigned short* __restrict__ contrib,
    const int* __restrict__ csr,
    float* __restrict__ out,
    float* __restrict__ sums)
{
    __shared__ float lsum[96], lq[96];
    int t = threadIdx.x;
    int rl = t / 24, c4 = t - rl * 24;
    float ps0 = 0.f, ps1 = 0.f, ps2 = 0.f, ps3 = 0.f;
    float pq0 = 0.f, pq1 = 0.f, pq2 = 0.f, pq3 = 0.f;

    for (int rb = blockIdx.x * 16; rb < N_OUT; rb += gridDim.x * 16) {
        int r = rb + rl;                       // N_OUT % 16 == 0
        int s = csr[r], e = csr[r + 1];
        float a0 = 0.f, a1 = 0.f, a2 = 0.f, a3 = 0.f;
        int j = s;
        for (; j + 1 < e; j += 2) {
            uint2 u = *(const uint2*)(contrib + (size_t)j * 96 + c4 * 4);
            uint2 v = *(const uint2*)(contrib + (size_t)(j + 1) * 96 + c4 * 4);
            a0 += b_lo(u.x); a1 += b_hi(u.x); a2 += b_lo(u.y); a3 += b_hi(u.y);
            a0 += b_lo(v.x); a1 += b_hi(v.x); a2 += b_lo(v.y); a3 += b_hi(v.y);
        }
        if (j < e) {
            uint2 u = *(const uint2*)(contrib + (size_t)j * 96 + c4 * 4);
            a0 += b_lo(u.x); a1 += b_hi(u.x); a2 += b_lo(u.y); a3 += b_hi(u.y);
        }
        *(float4*)(out + (size_t)r * 96 + c4 * 4) = make_float4(a0, a1, a2, a3);
        ps0 += a0; ps1 += a1; ps2 += a2; ps3 += a3;
        pq0 += a0 * a0; pq1 += a1 * a1; pq2 += a2 * a2; pq3 += a3 * a3;
    }

    if (t < 96) { lsum[t] = 0.f; lq[t] = 0.f; }
    __syncthreads();
    atomicAdd(&lsum[c4 * 4 + 0], ps0); atomicAdd(&lsum[c4 * 4 + 1], ps1);
    atomicAdd(&lsum[c4 * 4 + 2], ps2); atomicAdd(&lsum[c4 * 4 + 3], ps3);
    atomicAdd(&lq[c4 * 4 + 0], pq0);   atomicAdd(&lq[c4 * 4 + 1], pq1);
    atomicAdd(&lq[c4 * 4 + 2], pq2);   atomicAdd(&lq[c4 * 4 + 3], pq3);
    __syncthreads();
    if (t < 96) {
        atomicAdd(&sums[t], lsum[t]);
        atomicAdd(&sums[96 + t], lq[t]);
    }
}

__global__ void bn_final(float* __restrict__ sums, const float* __restrict__ gamma,
                         const float* __restrict__ beta) {
    int c = threadIdx.x;
    if (c < 96) {
        float mean = sums[c] * (1.0f / (float)N_OUT);
        float var  = sums[96 + c] * (1.0f / (float)N_OUT) - mean * mean;
        float inv  = rsqrtf(var + BN_EPS);
        float sc   = inv * gamma[c];
        sums[c]      = sc;
        sums[96 + c] = beta[c] - mean * sc;
    }
}

__global__ void bn_apply(float* __restrict__ out, const float* __restrict__ sums) {
    int t = blockIdx.x * 256 + threadIdx.x;
    int g = t % 24;
    float sc0 = sums[g * 4 + 0], sc1 = sums[g * 4 + 1];
    float sc2 = sums[g * 4 + 2], sc3 = sums[g * 4 + 3];
    float sh0 = sums[96 + g * 4 + 0], sh1 = sums[96 + g * 4 + 1];
    float sh2 = sums[96 + g * 4 + 2], sh3 = sums[96 + g * 4 + 3];
    float4* o4 = (float4*)out;
    for (long f = t; f < 14400000L; f += 258048) {
        float4 v = o4[f];
        v.x = fmaxf(v.x * sc0 + sh0, 0.f);
        v.y = fmaxf(v.y * sc1 + sh1, 0.f);
        v.z = fmaxf(v.z * sc2 + sh2, 0.f);
        v.w = fmaxf(v.w * sc3 + sh3, 0.f);
        o4[f] = v;
    }
}

extern "C" void kernel_launch(void* const* d_in, const int* in_sizes, int n_in,
                              void* d_out, int out_size, void* d_ws, size_t ws_size,
                              hipStream_t stream) {
    const float* feats  = (const float*)d_in[0];
    const int* in_idx   = (const int*)d_in[1];
    const int* out_idx  = (const int*)d_in[2];
    const float* weight = (const float*)d_in[3];
    const float* gamma  = (const float*)d_in[4];
    const float* beta   = (const float*)d_in[5];
    float* out = (float*)d_out;

    char* ws = (char*)d_ws;
    size_t off = 0;
    unsigned short* fb      = (unsigned short*)(ws + off); off += 38400000;
    unsigned short* wt      = (unsigned short*)(ws + off); off += 497664;
    unsigned short* contrib = (unsigned short*)(ws + off); off += (size_t)NPAIR * 96 * 2;
    int* counts             = (int*)(ws + off); off += 2400000;
    int* csr                = (int*)(ws + off); off += 2400016;
    int* bsum               = (int*)(ws + off); off += 4096;
    int* bsum_ex            = (int*)(ws + off); off += 4096;
    int* lrank              = (int*)(ws + off); off += (size_t)NPAIR * 4;
    float* sums             = (float*)(ws + off); off += 768;

    hipMemsetAsync(counts, 0, (size_t)N_OUT * sizeof(int), stream);
    hipMemsetAsync(sums, 0, 192 * sizeof(float), stream);

    cvt_feats<<<9375, 256, 0, stream>>>(feats, fb);
    cvt_w<<<972, 256, 0, stream>>>(weight, wt);

    k_hist<<<(NPAIR + 255) / 256, 256, 0, stream>>>(out_idx, counts, lrank);
    k_bsum<<<586, 256, 0, stream>>>(counts, bsum);
    k_scan_bsum<<<1, 1024, 0, stream>>>(bsum, bsum_ex);
    k_scan_local<<<586, 256, 0, stream>>>(counts, bsum_ex, csr);

    contrib_k<<<dim3(2344, KOFF), 256, 0, stream>>>(fb, wt, in_idx, out_idx, csr, lrank, contrib);

    reduce_bn<<<9375, 384, 0, stream>>>(contrib, csr, out, sums);
    bn_final<<<1, 128, 0, stream>>>(sums, gamma, beta);
    bn_apply<<<1008, 256, 0, stream>>>(out, sums);
}

// Round 2
// 1428.609 us; speedup vs baseline: 1.0807x; 1.0807x over previous
//
#include <hip/hip_runtime.h>
#include <hip/hip_bf16.h>

#define N_IN   200000
#define N_OUT  600000
#define KOFF   27
#define PPAIR  150000
#define NPAIR  (KOFF * PPAIR)       // 4,050,000
#define C      96
#define BN_EPS 1e-5f

using bf16x8 = __attribute__((ext_vector_type(8))) __bf16;
using f32x4  = __attribute__((ext_vector_type(4))) float;
using u32x4  = __attribute__((ext_vector_type(4))) unsigned int;

static __device__ __forceinline__ unsigned short f2b(float x) {
    __hip_bfloat16 h = __float2bfloat16(x);
    return *reinterpret_cast<unsigned short*>(&h);
}
static __device__ __forceinline__ float b_lo(unsigned int u) { return __uint_as_float(u << 16); }
static __device__ __forceinline__ float b_hi(unsigned int u) { return __uint_as_float(u & 0xffff0000u); }

// ---- feats fp32 -> bf16, 8 elems/thread. 19,200,000 = 9375*256*8 exactly.
__global__ void cvt_feats(const float* __restrict__ src, unsigned short* __restrict__ dst) {
    int t = blockIdx.x * 256 + threadIdx.x;
    const float4* s4 = (const float4*)src;
    float4 a = s4[2 * t], b = s4[2 * t + 1];
    union { unsigned short u[8]; uint4 v; } r;
    r.u[0] = f2b(a.x); r.u[1] = f2b(a.y); r.u[2] = f2b(a.z); r.u[3] = f2b(a.w);
    r.u[4] = f2b(b.x); r.u[5] = f2b(b.y); r.u[6] = f2b(b.z); r.u[7] = f2b(b.w);
    ((uint4*)dst)[t] = r.v;
}

// ---- weight [k][c_in][c_out] fp32 -> wt [k][c_out][c_in] bf16
__global__ void cvt_w(const float* __restrict__ w, unsigned short* __restrict__ wt) {
    int t = blockIdx.x * 256 + threadIdx.x;   // 972*256 = 248832 exactly
    int k = t / 9216;
    int rem = t - k * 9216;
    int o = rem / 96;
    int i = rem - o * 96;
    wt[t] = f2b(w[k * 9216 + i * 96 + o]);
}

// ---- counting sort of out_idx --------------------------------------------
// hist + local rank in ONE pass: the atomicAdd return value IS the local rank.
__global__ void k_hist(const int* __restrict__ out_idx, int* __restrict__ counts,
                       int* __restrict__ lrank) {
    int t = blockIdx.x * 256 + threadIdx.x;
    if (t < NPAIR) lrank[t] = atomicAdd(&counts[out_idx[t]], 1);
}

__global__ void k_bsum(const int* __restrict__ counts, int* __restrict__ bsum) {
    __shared__ int ls[256];
    int b = blockIdx.x, t = threadIdx.x;
    int base = b * 1024 + t * 4;
    int s = 0;
#pragma unroll
    for (int j = 0; j < 4; j++) { int i = base + j; if (i < N_OUT) s += counts[i]; }
    ls[t] = s;
    __syncthreads();
    for (int off = 128; off > 0; off >>= 1) {
        if (t < off) ls[t] += ls[t + off];
        __syncthreads();
    }
    if (t == 0) bsum[b] = ls[0];
}

__global__ void k_scan_bsum(const int* __restrict__ bsum, int* __restrict__ bsum_ex) {
    __shared__ int sc[1024];
    int t = threadIdx.x;
    int v = (t < 586) ? bsum[t] : 0;
    sc[t] = v;
    __syncthreads();
    for (int off = 1; off < 1024; off <<= 1) {
        int add = (t >= off) ? sc[t - off] : 0;
        __syncthreads();
        sc[t] += add;
        __syncthreads();
    }
    bsum_ex[t] = sc[t] - v;   // exclusive
}

__global__ void k_scan_local(const int* __restrict__ counts, const int* __restrict__ bsum_ex,
                             int* __restrict__ csr) {
    __shared__ int sc[256];
    int b = blockIdx.x, t = threadIdx.x;
    int base = b * 1024 + t * 4;
    int c[4];
    int s = 0;
#pragma unroll
    for (int j = 0; j < 4; j++) {
        int i = base + j;
        c[j] = (i < N_OUT) ? counts[i] : 0;
        s += c[j];
    }
    sc[t] = s;
    __syncthreads();
    for (int off = 1; off < 256; off <<= 1) {
        int add = (t >= off) ? sc[t - off] : 0;
        __syncthreads();
        sc[t] += add;
        __syncthreads();
    }
    int run = bsum_ex[b] + sc[t] - s;
#pragma unroll
    for (int j = 0; j < 4; j++) {
        int i = base + j;
        if (i < N_OUT) {
            csr[i] = run;
            run += c[j];
            if (i == N_OUT - 1) csr[N_OUT] = run;
        }
    }
}

// ---- Phase A: gather -> transposed MFMA -> in-register quad repack -> full-sector scatter
// mfma(b, a, acc) computes D^T: lane (q,l16) holds channels n*16+q*4+{0..3} of
// pair row l16. A cross-quad __shfl repack gives each lane 8 CONSECUTIVE
// channels (q*8 + s*32 + 0..7), so each uint4 store instruction covers a full
// aligned 64B sector per row (rows are 192B = 3 sectors) -> no write-allocate
// RMW fetch. No LDS repack, no extra barrier.
__global__ __launch_bounds__(256, 6) void contrib_k(
    const unsigned short* __restrict__ fb,   // feats bf16 [N_IN][96]
    const unsigned short* __restrict__ wt,   // weight bf16 [27][96(out)][96(in)]
    const int* __restrict__ in_idx,
    const int* __restrict__ out_idx,
    const int* __restrict__ csr,
    const int* __restrict__ lrank,
    unsigned short* __restrict__ contrib)    // [NPAIR][96] bf16, sorted by out_idx
{
    __shared__ int s_g[64];
    __shared__ int s_rank[64];

    const int t    = threadIdx.x;
    const int k    = blockIdx.y;
    const int row0 = blockIdx.x * 64;
    const long kp  = (long)k * PPAIR;

    if (t < 64) {
        int p  = row0 + t;
        int pc = (p < PPAIR) ? p : (PPAIR - 1);
        s_g[t]    = in_idx[kp + pc];
        s_rank[t] = (p < PPAIR) ? (csr[out_idx[kp + p]] + lrank[kp + p]) : -1;
    }
    __syncthreads();

    const int wave = t >> 6, lane = t & 63;
    const int quad = lane >> 4, l16 = lane & 15;

    const unsigned short* arow  = fb + (size_t)s_g[wave * 16 + l16] * 96 + quad * 8;
    const unsigned short* bbase = wt + (size_t)k * 9216 + l16 * 96 + quad * 8;

    f32x4 acc[6];
#pragma unroll
    for (int n = 0; n < 6; n++) acc[n] = (f32x4){0.f, 0.f, 0.f, 0.f};

#pragma unroll
    for (int kk = 0; kk < 3; kk++) {
        bf16x8 a = *(const bf16x8*)(arow + kk * 32);
#pragma unroll
        for (int n = 0; n < 6; n++) {
            bf16x8 b = *(const bf16x8*)(bbase + n * 16 * 96 + kk * 32);
            // swapped operands: acc[n] = (W^T)(feats^T) block -> D^T
            acc[n] = __builtin_amdgcn_mfma_f32_16x16x32_bf16(b, a, acc[n], 0, 0, 0);
        }
    }

    // pack each acc quadruple into 2 u32 (4 bf16): pk[n][rr] = channels n*16+quad*4+{2rr,2rr+1}
    unsigned int pk[6][2];
#pragma unroll
    for (int n = 0; n < 6; n++) {
        pk[n][0] = (unsigned)f2b(acc[n][0]) | ((unsigned)f2b(acc[n][1]) << 16);
        pk[n][1] = (unsigned)f2b(acc[n][2]) | ((unsigned)f2b(acc[n][3]) << 16);
    }

    // cross-quad exchange: target lane (q,l16) gets channels q*8+s*32+{0..7}
    // from source quads 2(q&1) and 2(q&1)+1 with n = 2s + (q>>1).
    const int rk   = s_rank[wave * 16 + l16];
    const int srcA = ((quad & 1) << 5) + l16;   // quad 2(q&1), same l16 (same row)
    const int srcB = srcA + 16;                 // quad 2(q&1)+1
    const bool hi  = (quad >> 1) != 0;

#pragma unroll
    for (int s = 0; s < 3; s++) {
        unsigned a0 = (unsigned)__shfl((int)pk[2 * s][0], srcA);
        unsigned a1 = (unsigned)__shfl((int)pk[2 * s][1], srcA);
        unsigned a2 = (unsigned)__shfl((int)pk[2 * s][0], srcB);
        unsigned a3 = (unsigned)__shfl((int)pk[2 * s][1], srcB);
        unsigned b0 = (unsigned)__shfl((int)pk[2 * s + 1][0], srcA);
        unsigned b1 = (unsigned)__shfl((int)pk[2 * s + 1][1], srcA);
        unsigned b2 = (unsigned)__shfl((int)pk[2 * s + 1][0], srcB);
        unsigned b3 = (unsigned)__shfl((int)pk[2 * s + 1][1], srcB);
        u32x4 v;
        v.x = hi ? b0 : a0;
        v.y = hi ? b1 : a1;
        v.z = hi ? b2 : a2;
        v.w = hi ? b3 : a3;
        if (rk >= 0) {
            // bytes: rk*192 + s*64 + quad*16  -> 4 quads = one full 64B sector
            __builtin_nontemporal_store(
                v, (u32x4*)(contrib + (size_t)rk * 96 + s * 32 + quad * 8));
        }
    }
}

// ---- Phase B: sequential-slab reduction + fused BN stats ------------------
// block 384: rl = t/24 in [0,16) rows in flight, c4 = t%24 -> 4 channels/lane.
__global__ __launch_bounds__(384) void reduce_bn(
    const unsigned short* __restrict__ contrib,
    const int* __restrict__ csr,
    float* __restrict__ out,
    float* __restrict__ sums)
{
    __shared__ float lsum[96], lq[96];
    int t = threadIdx.x;
    int rl = t / 24, c4 = t - rl * 24;
    float ps0 = 0.f, ps1 = 0.f, ps2 = 0.f, ps3 = 0.f;
    float pq0 = 0.f, pq1 = 0.f, pq2 = 0.f, pq3 = 0.f;

    for (int rb = blockIdx.x * 16; rb < N_OUT; rb += gridDim.x * 16) {
        int r = rb + rl;                       // N_OUT % 16 == 0
        int s = csr[r], e = csr[r + 1];
        float a0 = 0.f, a1 = 0.f, a2 = 0.f, a3 = 0.f;
        int j = s;
        for (; j + 1 < e; j += 2) {
            unsigned long long u = __builtin_nontemporal_load(
                (const unsigned long long*)(contrib + (size_t)j * 96 + c4 * 4));
            unsigned long long v = __builtin_nontemporal_load(
                (const unsigned long long*)(contrib + (size_t)(j + 1) * 96 + c4 * 4));
            unsigned ux = (unsigned)u, uy = (unsigned)(u >> 32);
            unsigned vx = (unsigned)v, vy = (unsigned)(v >> 32);
            a0 += b_lo(ux); a1 += b_hi(ux); a2 += b_lo(uy); a3 += b_hi(uy);
            a0 += b_lo(vx); a1 += b_hi(vx); a2 += b_lo(vy); a3 += b_hi(vy);
        }
        if (j < e) {
            unsigned long long u = __builtin_nontemporal_load(
                (const unsigned long long*)(contrib + (size_t)j * 96 + c4 * 4));
            unsigned ux = (unsigned)u, uy = (unsigned)(u >> 32);
            a0 += b_lo(ux); a1 += b_hi(ux); a2 += b_lo(uy); a3 += b_hi(uy);
        }
        *(float4*)(out + (size_t)r * 96 + c4 * 4) = make_float4(a0, a1, a2, a3);
        ps0 += a0; ps1 += a1; ps2 += a2; ps3 += a3;
        pq0 += a0 * a0; pq1 += a1 * a1; pq2 += a2 * a2; pq3 += a3 * a3;
    }

    if (t < 96) { lsum[t] = 0.f; lq[t] = 0.f; }
    __syncthreads();
    atomicAdd(&lsum[c4 * 4 + 0], ps0); atomicAdd(&lsum[c4 * 4 + 1], ps1);
    atomicAdd(&lsum[c4 * 4 + 2], ps2); atomicAdd(&lsum[c4 * 4 + 3], ps3);
    atomicAdd(&lq[c4 * 4 + 0], pq0);   atomicAdd(&lq[c4 * 4 + 1], pq1);
    atomicAdd(&lq[c4 * 4 + 2], pq2);   atomicAdd(&lq[c4 * 4 + 3], pq3);
    __syncthreads();
    if (t < 96) {
        atomicAdd(&sums[t], lsum[t]);
        atomicAdd(&sums[96 + t], lq[t]);
    }
}

__global__ void bn_final(float* __restrict__ sums, const float* __restrict__ gamma,
                         const float* __restrict__ beta) {
    int c = threadIdx.x;
    if (c < 96) {
        float mean = sums[c] * (1.0f / (float)N_OUT);
        float var  = sums[96 + c] * (1.0f / (float)N_OUT) - mean * mean;
        float inv  = rsqrtf(var + BN_EPS);
        float sc   = inv * gamma[c];
        sums[c]      = sc;
        sums[96 + c] = beta[c] - mean * sc;
    }
}

__global__ void bn_apply(float* __restrict__ out, const float* __restrict__ sums) {
    int t = blockIdx.x * 256 + threadIdx.x;
    int g = t % 24;
    float sc0 = sums[g * 4 + 0], sc1 = sums[g * 4 + 1];
    float sc2 = sums[g * 4 + 2], sc3 = sums[g * 4 + 3];
    float sh0 = sums[96 + g * 4 + 0], sh1 = sums[96 + g * 4 + 1];
    float sh2 = sums[96 + g * 4 + 2], sh3 = sums[96 + g * 4 + 3];
    f32x4* o4 = (f32x4*)out;
    for (long f = t; f < 14400000L; f += 258048) {
        f32x4 v = __builtin_nontemporal_load(o4 + f);
        v.x = fmaxf(v.x * sc0 + sh0, 0.f);
        v.y = fmaxf(v.y * sc1 + sh1, 0.f);
        v.z = fmaxf(v.z * sc2 + sh2, 0.f);
        v.w = fmaxf(v.w * sc3 + sh3, 0.f);
        __builtin_nontemporal_store(v, o4 + f);
    }
}

extern "C" void kernel_launch(void* const* d_in, const int* in_sizes, int n_in,
                              void* d_out, int out_size, void* d_ws, size_t ws_size,
                              hipStream_t stream) {
    const float* feats  = (const float*)d_in[0];
    const int* in_idx   = (const int*)d_in[1];
    const int* out_idx  = (const int*)d_in[2];
    const float* weight = (const float*)d_in[3];
    const float* gamma  = (const float*)d_in[4];
    const float* beta   = (const float*)d_in[5];
    float* out = (float*)d_out;

    char* ws = (char*)d_ws;
    size_t off = 0;
    unsigned short* fb      = (unsigned short*)(ws + off); off += 38400000;
    unsigned short* wt      = (unsigned short*)(ws + off); off += 497664;
    unsigned short* contrib = (unsigned short*)(ws + off); off += (size_t)NPAIR * 96 * 2;
    int* counts             = (int*)(ws + off); off += 2400000;
    int* csr                = (int*)(ws + off); off += 2400016;
    int* bsum               = (int*)(ws + off); off += 4096;
    int* bsum_ex            = (int*)(ws + off); off += 4096;
    int* lrank              = (int*)(ws + off); off += (size_t)NPAIR * 4;
    float* sums             = (float*)(ws + off); off += 768;

    hipMemsetAsync(counts, 0, (size_t)N_OUT * sizeof(int), stream);
    hipMemsetAsync(sums, 0, 192 * sizeof(float), stream);

    cvt_feats<<<9375, 256, 0, stream>>>(feats, fb);
    cvt_w<<<972, 256, 0, stream>>>(weight, wt);

    k_hist<<<(NPAIR + 255) / 256, 256, 0, stream>>>(out_idx, counts, lrank);
    k_bsum<<<586, 256, 0, stream>>>(counts, bsum);
    k_scan_bsum<<<1, 1024, 0, stream>>>(bsum, bsum_ex);
    k_scan_local<<<586, 256, 0, stream>>>(counts, bsum_ex, csr);

    contrib_k<<<dim3(2344, KOFF), 256, 0, stream>>>(fb, wt, in_idx, out_idx, csr, lrank, contrib);

    reduce_bn<<<9375, 384, 0, stream>>>(contrib, csr, out, sums);
    bn_final<<<1, 128, 0, stream>>>(sums, gamma, beta);
    bn_apply<<<1008, 256, 0, stream>>>(out, sums);
}